// Round 1
// baseline (476.950 us; speedup 1.0000x reference)
//
#include <hip/hip_runtime.h>

#define TLE 16          // fixed tile edge from reference (covers max bbox)
#define VOL_S 256
#define VOL_S2 (VOL_S * VOL_S)   // 65536

// One 256-thread block per Gaussian.
// Phase 1: threads 0..47 compute the three 1D exp tables (separable Gaussian)
//          plus per-axis bbox [min, min+dim).
// Phase 2: threads form a 16(y) x 16(z) sheet; loop over x; each valid lane
//          does one fp32 global atomicAdd per voxel. Lane = z => atomics are
//          contiguous along the volume's fastest axis (coalesced 64B runs).
__global__ __launch_bounds__(256) void splat_kernel(
    const float* __restrict__ centers,
    const float* __restrict__ sigmas,
    const float* __restrict__ intens,
    float* __restrict__ vol)
{
    const int g = blockIdx.x;
    __shared__ float sE[3][TLE];
    __shared__ int   sMin[3];
    __shared__ int   sDim[3];

    const int tid = threadIdx.x;

    if (tid < 48) {
        const int a = tid >> 4;   // axis 0..2
        const int t = tid & 15;   // tap 0..15
        const float c   = centers[g * 3 + a];
        const float sig = sigmas[g];
        const float cv  = c * 255.0f;                 // voxel-space center
        const float cut = 3.0f * sig * 255.0f;        // voxel-space cutoff
        const float mnf = floorf(fmaxf(cv - cut, 0.0f));
        const float mxf = fminf(floorf(fminf(cv + cut, 255.0f)) + 1.0f, 256.0f);
        const int mn  = (int)mnf;
        const int dim = (int)mxf - mn;                // 1..14 <= TLE
        if (t == 0) { sMin[a] = mn; sDim[a] = dim; }
        float e = 0.0f;                               // 0 = invalid sentinel
        if (t < dim) {
            const float d = (float)(mn + t) * (1.0f / 255.0f) - c;
            const float inv2s2 = 0.5f / (sig * sig);
            e = __expf(-(d * d) * inv2s2);            // valid e >= exp(-4.5) ~ 0.011 > 0
            if (a == 0) e *= intens[g];               // fold intensity into x-table
        }
        sE[a][t] = e;
    }
    __syncthreads();

    const int z = tid & 15;
    const int y = tid >> 4;
    const float fyz = sE[1][y] * sE[2][z];
    if (fyz == 0.0f) return;                          // lane outside bbox in y or z

    const int ybase = (sMin[1] + y) * VOL_S + (sMin[2] + z);
    float* base = vol + (size_t)sMin[0] * VOL_S2 + ybase;
    const int dx = sDim[0];
    #pragma unroll 4
    for (int i = 0; i < dx; ++i) {
        atomicAdd(base + (size_t)i * VOL_S2, sE[0][i] * fyz);
    }
}

extern "C" void kernel_launch(void* const* d_in, const int* in_sizes, int n_in,
                              void* d_out, int out_size, void* d_ws, size_t ws_size,
                              hipStream_t stream) {
    const float* centers = (const float*)d_in[0];   // (N,3)
    const float* sigmas  = (const float*)d_in[1];   // (N,)
    const float* intens  = (const float*)d_in[2];   // (N,)
    float* vol = (float*)d_out;                     // 256^3 fp32
    const int N = in_sizes[1];

    // Harness poisons d_out with 0xAA before every launch — zero it ourselves.
    hipMemsetAsync(d_out, 0, (size_t)out_size * sizeof(float), stream);
    splat_kernel<<<N, 256, 0, stream>>>(centers, sigmas, intens, vol);
}

// Round 2
// 168.103 us; speedup vs baseline: 2.8372x; 2.8372x over previous
//
#include <hip/hip_runtime.h>

// ---------------------------------------------------------------------------
// Gather formulation: bin Gaussians into 16^3-voxel tiles, then one block per
// tile accumulates all its Gaussians into per-thread register accumulators and
// writes each voxel exactly once. No global atomics on the volume, no output
// memset (every voxel stored).
//
// Volume 256^3, tiles 16^3 -> 16x16x16 = 4096 tiles. Max bbox width 14 voxels
// => a Gaussian touches at most 2 tiles per axis (<= 8 tiles).
// ---------------------------------------------------------------------------

#define NT3   4096            // number of tiles
#define INV255 (1.0f/255.0f)

// ---- kernel 1: per-Gaussian precompute + per-tile counts -------------------
__global__ __launch_bounds__(256) void count_prep_kernel(
    const float* __restrict__ centers,
    const float* __restrict__ sigmas,
    const float* __restrict__ intens,
    int*   __restrict__ counts,
    float* __restrict__ prep,   // 8 floats per gaussian
    int N)
{
    int g = blockIdx.x * 256 + threadIdx.x;
    if (g >= N) return;
    float c[3] = {centers[3*g+0], centers[3*g+1], centers[3*g+2]};
    float sig  = sigmas[g];
    float cut  = 3.0f * sig * 255.0f;
    int mn[3], mx[3];
    #pragma unroll
    for (int a = 0; a < 3; ++a) {
        float cv = c[a] * 255.0f;
        mn[a] = (int)floorf(fmaxf(cv - cut, 0.0f));
        mx[a] = (int)fminf(floorf(fminf(cv + cut, 255.0f)) + 1.0f, 256.0f); // exclusive, <=256
    }
    unsigned mnp = (unsigned)mn[0] | ((unsigned)mn[1] << 10) | ((unsigned)mn[2] << 20);
    unsigned mxp = (unsigned)mx[0] | ((unsigned)mx[1] << 10) | ((unsigned)mx[2] << 20);
    float* p = prep + 8 * g;
    p[0] = c[0]; p[1] = c[1]; p[2] = c[2];
    p[3] = 0.5f / (sig * sig);
    p[4] = intens[g];
    p[5] = __uint_as_float(mnp);
    p[6] = __uint_as_float(mxp);
    p[7] = 0.0f;
    int t0x = mn[0] >> 4, t1x = (mx[0] - 1) >> 4;
    int t0y = mn[1] >> 4, t1y = (mx[1] - 1) >> 4;
    int t0z = mn[2] >> 4, t1z = (mx[2] - 1) >> 4;
    for (int tx = t0x; tx <= t1x; ++tx)
        for (int ty = t0y; ty <= t1y; ++ty)
            for (int tz = t0z; tz <= t1z; ++tz)
                atomicAdd(&counts[(tx << 8) | (ty << 4) | tz], 1);
}

// ---- kernel 2: exclusive scan of 4096 counts (single block) ----------------
__global__ __launch_bounds__(256) void scan_kernel(
    const int* __restrict__ counts,
    int* __restrict__ offsets,
    int* __restrict__ cursor)
{
    __shared__ int lds[256];
    int tid = threadIdx.x;
    int local[16];
    int s = 0;
    #pragma unroll
    for (int j = 0; j < 16; ++j) { local[j] = s; s += counts[tid * 16 + j]; }
    lds[tid] = s;
    __syncthreads();
    // Hillis-Steele inclusive scan over 256 partials
    for (int off = 1; off < 256; off <<= 1) {
        int v = (tid >= off) ? lds[tid - off] : 0;
        __syncthreads();
        lds[tid] += v;
        __syncthreads();
    }
    int base = lds[tid] - s;     // exclusive prefix of this thread's chunk
    #pragma unroll
    for (int j = 0; j < 16; ++j) {
        int o = base + local[j];
        offsets[tid * 16 + j] = o;
        cursor [tid * 16 + j] = o;
    }
}

// ---- kernel 3: fill per-tile gaussian lists --------------------------------
__global__ __launch_bounds__(256) void fill_kernel(
    const float* __restrict__ prep,
    int* __restrict__ cursor,
    int* __restrict__ list,
    int N)
{
    int g = blockIdx.x * 256 + threadIdx.x;
    if (g >= N) return;
    unsigned mnp = __float_as_uint(prep[8 * g + 5]);
    unsigned mxp = __float_as_uint(prep[8 * g + 6]);
    int t0x = (int)( mnp        & 1023) >> 4, t1x = ((int)( mxp        & 1023) - 1) >> 4;
    int t0y = (int)((mnp >> 10) & 1023) >> 4, t1y = ((int)((mxp >> 10) & 1023) - 1) >> 4;
    int t0z = (int)((mnp >> 20) & 1023) >> 4, t1z = ((int)((mxp >> 20) & 1023) - 1) >> 4;
    for (int tx = t0x; tx <= t1x; ++tx)
        for (int ty = t0y; ty <= t1y; ++ty)
            for (int tz = t0z; tz <= t1z; ++tz) {
                int t = (tx << 8) | (ty << 4) | tz;
                int slot = atomicAdd(&cursor[t], 1);
                list[slot] = g;
            }
}

// ---- kernel 4: main gather — one block per 16^3 tile -----------------------
// Thread (ly=tid>>4, lz=tid&15) owns voxels (ox+0..15, oy+ly, oz+lz) in regs.
// Waves are autonomous: no __syncthreads in the Gaussian loop.
__global__ __launch_bounds__(256) void splat_main(
    const float* __restrict__ prep,
    const int*   __restrict__ offsets,
    const int*   __restrict__ counts,
    const int*   __restrict__ list,
    float* __restrict__ vol)
{
    int b  = blockIdx.x;
    int ox = (b >> 8) << 4, oy = ((b >> 4) & 15) << 4, oz = (b & 15) << 4;
    int tid  = threadIdx.x;
    int ly   = tid >> 4, lz = tid & 15;
    int lane = tid & 63;
    int tap  = lane & 15;                 // x tap this lane computes (lanes mod 16)

    float acc[16];
    #pragma unroll
    for (int i = 0; i < 16; ++i) acc[i] = 0.0f;

    int start = offsets[b];
    int n     = counts[b];

    int   iy = oy + ly, iz = oz + lz, ix = ox + tap;
    float fy = (float)iy * INV255;
    float fz = (float)iz * INV255;
    float fx = (float)ix * INV255;

    for (int k = 0; k < n; ++k) {
        int g = __builtin_amdgcn_readfirstlane(list[start + k]);   // SGPR -> scalar loads
        const float* p = prep + 8 * g;
        float cx = p[0], cy = p[1], cz = p[2];
        float inv2s2 = p[3], inten = p[4];
        unsigned mnp = __float_as_uint(p[5]);
        unsigned mxp = __float_as_uint(p[6]);
        int mnx = (int)( mnp        & 1023), mxx = (int)( mxp        & 1023);
        int mny = (int)((mnp >> 10) & 1023), mxy = (int)((mxp >> 10) & 1023);
        int mnz = (int)((mnp >> 20) & 1023), mxz = (int)((mxp >> 20) & 1023);

        float dy = fy - cy, dz = fz - cz;
        float ey = (iy >= mny && iy < mxy) ? __expf(-dy * dy * inv2s2) : 0.0f;
        float ez = (iz >= mnz && iz < mxz) ? __expf(-dz * dz * inv2s2) : 0.0f;
        float fyz = ey * ez * inten;
        if (__ballot(fyz != 0.0f) == 0ULL) continue;   // gaussian misses this wave's y-slab

        float dx = fx - cx;
        float ex = (ix >= mnx && ix < mxx) ? __expf(-dx * dx * inv2s2) : 0.0f;
        int exb = __float_as_int(ex);
        #pragma unroll
        for (int i = 0; i < 16; ++i) {
            float sx = __int_as_float(__builtin_amdgcn_readlane(exb, i)); // x-table bcast via SGPR
            acc[i] = fmaf(sx, fyz, acc[i]);
        }
    }

    int baseIdx = (iy << 8) + iz;          // y*256 + z
    #pragma unroll
    for (int i = 0; i < 16; ++i)
        vol[((ox + i) << 16) + baseIdx] = acc[i];
}

// ---------------------------------------------------------------------------
extern "C" void kernel_launch(void* const* d_in, const int* in_sizes, int n_in,
                              void* d_out, int out_size, void* d_ws, size_t ws_size,
                              hipStream_t stream) {
    const float* centers = (const float*)d_in[0];   // (N,3)
    const float* sigmas  = (const float*)d_in[1];   // (N,)
    const float* intens  = (const float*)d_in[2];   // (N,)
    float* vol = (float*)d_out;                     // 256^3 fp32
    const int N = in_sizes[1];

    // workspace layout
    char* ws = (char*)d_ws;
    int*   counts  = (int*)(ws);                       // 4096 ints
    int*   offsets = (int*)(ws + 16 * 1024);           // 4096 ints
    int*   cursor  = (int*)(ws + 32 * 1024);           // 4096 ints
    float* prep    = (float*)(ws + 48 * 1024);         // N * 8 floats
    int*   list    = (int*)(ws + 48 * 1024 + (size_t)N * 8 * sizeof(float)); // <= 8N ints

    hipMemsetAsync(counts, 0, NT3 * sizeof(int), stream);

    int gblocks = (N + 255) / 256;
    count_prep_kernel<<<gblocks, 256, 0, stream>>>(centers, sigmas, intens, counts, prep, N);
    scan_kernel<<<1, 256, 0, stream>>>(counts, offsets, cursor);
    fill_kernel<<<gblocks, 256, 0, stream>>>(prep, cursor, list, N);
    splat_main<<<NT3, 256, 0, stream>>>(prep, offsets, counts, list, vol);
}